// Round 1
// baseline (262.702 us; speedup 1.0000x reference)
//
#include <hip/hip_runtime.h>

#define M_ROWS 12608          // 64*197
#define M_PAD  12800          // 50*256 (GEMM row padding)
#define K_DIM  768
#define QSZ    9682944        // 64*12*197*64 elements per q/k/v plane
#define XB_ELEMS (12800*768)  // padded bf16 X copy (lives in d_out scratch)

typedef __bf16 bf16x8 __attribute__((ext_vector_type(8)));
typedef float  f32x4  __attribute__((ext_vector_type(4)));

__device__ __forceinline__ unsigned short f2bf(float f) {
    unsigned u = __builtin_bit_cast(unsigned, f);
    u += 0x7fffu + ((u >> 16) & 1u);          // RNE, inputs are finite
    return (unsigned short)(u >> 16);
}

__device__ __forceinline__ void gll16(const unsigned short* g, unsigned short* l) {
    __builtin_amdgcn_global_load_lds(
        (const __attribute__((address_space(1))) unsigned int*)g,
        (__attribute__((address_space(3))) unsigned int*)l, 16, 0, 0);
}

__device__ __forceinline__ void cfence() { asm volatile("" ::: "memory"); }

// ---------------- Kernel 0: X fp32 -> bf16 (padded to 12800 rows, pad zeroed) ---------
__global__ void x2bf_kernel(const float* __restrict__ X, unsigned short* __restrict__ Xb) {
    size_t base = ((size_t)blockIdx.x * 256 + threadIdx.x) * 8;
    if (base >= (size_t)M_ROWS * K_DIM) {   // zero the pad rows (12608..12799)
        *(ushort4*)(Xb + base) = (ushort4){0, 0, 0, 0};
        *(ushort4*)(Xb + base + 4) = (ushort4){0, 0, 0, 0};
        return;
    }
    float4 a = *(const float4*)(X + base);
    float4 b = *(const float4*)(X + base + 4);
    ushort4 lo, hi;
    lo.x = f2bf(a.x); lo.y = f2bf(a.y); lo.z = f2bf(a.z); lo.w = f2bf(a.w);
    hi.x = f2bf(b.x); hi.y = f2bf(b.y); hi.z = f2bf(b.z); hi.w = f2bf(b.w);
    *(ushort4*)(Xb + base) = lo;
    *(ushort4*)(Xb + base + 4) = hi;
}

// ---------------- Kernel 1: W [768,2304] fp32 -> Wt [2304,768] bf16 ----------------
__global__ void wtrans_kernel(const float* __restrict__ W, unsigned short* __restrict__ Wt) {
    __shared__ float tile[32][33];
    int n0 = blockIdx.x * 32, k0 = blockIdx.y * 32;
    int tx = threadIdx.x, ty = threadIdx.y;
#pragma unroll
    for (int i = 0; i < 4; ++i)
        tile[ty + i * 8][tx] = W[(size_t)(k0 + ty + i * 8) * 2304 + n0 + tx];
    __syncthreads();
#pragma unroll
    for (int i = 0; i < 4; ++i)
        Wt[(size_t)(n0 + ty + i * 8) * K_DIM + k0 + tx] = f2bf(tile[tx][ty + i * 8]);
}

// ---------------- Kernel 2: QKV GEMM, 256x256 tile, 8 waves, 4-deep LDS ring ----------
// T3+T4: counted vmcnt(8) once per K-tile (never 0 in the loop), raw s_barrier (no
// implicit drain), 2 phases x 16 MFMA per K-tile with stage-issue interleaved. T5:
// setprio around MFMA clusters. T1: bijective XCD-chunked block swizzle (450 = 8*56+2).
// LDS ring: compute kt from buf[kt&3], stage kt+3 into buf[(kt+3)&3] -> writer and
// readers always 3 tiles apart, so vmcnt(8) (= kt+2,kt+3 in flight) is safe.
__global__ __launch_bounds__(512, 2) void qkv_gemm_kernel(
        const unsigned short* __restrict__ Xb, const unsigned short* __restrict__ Wt,
        const float* __restrict__ bias, unsigned short* __restrict__ qkv) {
    __shared__ __align__(16) unsigned short As[4][8192];   // 4 x 16 KB (256 rows x 32 k)
    __shared__ __align__(16) unsigned short Bs[4][8192];   // 4 x 16 KB

    // XCD-chunked bijective swizzle: 450 blocks, q=56, r=2
    const int lin = blockIdx.x;
    const int xcd = lin & 7, ix = lin >> 3;
    const int wg = (xcd < 2) ? xcd * 57 + ix : 114 + (xcd - 2) * 56 + ix;
    const int by = wg / 9, bx = wg - by * 9;
    const int m0 = by * 256, n0 = bx * 256;

    const int t = threadIdx.x;
    const int w = t >> 6, lane = t & 63, quad = lane >> 4, l16 = lane & 15;
    const int wr = w >> 2, wc = w & 3;      // wave -> (M-half, N-quarter)

    // staging: thread t owns chunks t (kc=t>>8) and t+512 (kc=t>>8+2), same row t&255
    const unsigned short* aP = Xb + (size_t)(m0 + (t & 255)) * K_DIM + (t >> 8) * 8;
    const unsigned short* bP = Wt + (size_t)(n0 + (t & 255)) * K_DIM + (t >> 8) * 8;

    // LDS frag read offsets (k-major chunk layout [kc][row][8]; 0 bank conflicts)
    const int aOff = (quad * 256 + wr * 128 + l16) * 8;
    const int bOff = (quad * 256 + wc * 64 + l16) * 8;

    f32x4 acc[8][4];
#pragma unroll
    for (int i = 0; i < 8; ++i)
#pragma unroll
        for (int j = 0; j < 4; ++j) acc[i][j] = (f32x4){0.f, 0.f, 0.f, 0.f};

    // prologue: stage K-tiles 0..2, land tile 0, keep 8 loads in flight
#pragma unroll
    for (int kt = 0; kt < 3; ++kt) {
        gll16(aP + kt * 32,      &As[kt][w * 512]);
        gll16(aP + kt * 32 + 16, &As[kt][4096 + w * 512]);
        gll16(bP + kt * 32,      &Bs[kt][w * 512]);
        gll16(bP + kt * 32 + 16, &Bs[kt][4096 + w * 512]);
    }
    asm volatile("s_waitcnt vmcnt(8)" ::: "memory");
    __builtin_amdgcn_s_barrier();
    cfence();

    for (int kt = 0; kt < 24; ++kt) {
        const int buf = kt & 3, sb = (kt + 3) & 3;
        const unsigned short* Ab = As[buf];
        const unsigned short* Bb = Bs[buf];
        const int sk = (kt + 3) * 32;   // kt>=21 stages dummy tiles (harmless, in-alloc)

        bf16x8 af[4], bfj[4];
        // ---- phase 0: read A rows 0..63(of wave half) + all B frags; stage A(kt+3)
#pragma unroll
        for (int i = 0; i < 4; ++i) af[i] = *(const bf16x8*)&Ab[aOff + i * 128];
#pragma unroll
        for (int j = 0; j < 4; ++j) bfj[j] = *(const bf16x8*)&Bb[bOff + j * 128];
        gll16(aP + sk,      &As[sb][w * 512]);
        gll16(aP + sk + 16, &As[sb][4096 + w * 512]);
        cfence();
        __builtin_amdgcn_s_barrier();
        cfence();
        __builtin_amdgcn_s_setprio(1);
#pragma unroll
        for (int i = 0; i < 4; ++i)
#pragma unroll
            for (int j = 0; j < 4; ++j)
                acc[i][j] = __builtin_amdgcn_mfma_f32_16x16x32_bf16(af[i], bfj[j], acc[i][j], 0, 0, 0);
        __builtin_amdgcn_s_setprio(0);
        cfence();
        __builtin_amdgcn_s_barrier();
        cfence();

        // ---- phase 1: read A rows 64..127; stage B(kt+3); counted checkpoint
#pragma unroll
        for (int i = 0; i < 4; ++i) af[i] = *(const bf16x8*)&Ab[aOff + 512 + i * 128];
        gll16(bP + sk,      &Bs[sb][w * 512]);
        gll16(bP + sk + 16, &Bs[sb][4096 + w * 512]);
        cfence();
        __builtin_amdgcn_s_barrier();
        cfence();
        __builtin_amdgcn_s_setprio(1);
#pragma unroll
        for (int i = 0; i < 4; ++i)
#pragma unroll
            for (int j = 0; j < 4; ++j)
                acc[i + 4][j] = __builtin_amdgcn_mfma_f32_16x16x32_bf16(af[i], bfj[j], acc[i + 4][j], 0, 0, 0);
        __builtin_amdgcn_s_setprio(0);
        // drain exactly to kt+1 landed; kt+2,kt+3 (8 loads) stay in flight
        asm volatile("s_waitcnt vmcnt(8)" ::: "memory");
        __builtin_amdgcn_s_barrier();
        cfence();
    }

    // epilogue: bias; fold 1/8 into q; q,k,v stored [b,h][tok][d]
    const int which = bx / 3;   // tiles 0-2 -> q, 3-5 -> k, 6-8 -> v (block-uniform)
#pragma unroll
    for (int j = 0; j < 4; ++j) {
        const int gn = n0 + wc * 64 + j * 16 + l16;
        const float bv = bias[gn];
        const int rem = gn - which * 768;
        const int hh = rem >> 6, dd = rem & 63;
#pragma unroll
        for (int i = 0; i < 8; ++i) {
            const int gm0 = m0 + wr * 128 + i * 16 + quad * 4;
#pragma unroll
            for (int r = 0; r < 4; ++r) {
                const int gm = gm0 + r;
                if (gm >= M_ROWS) continue;
                const int bb = gm / 197;
                const int tok = gm - bb * 197;
                float val = acc[i][j][r] + bv;
                if (which == 0) val *= 0.125f;
                size_t dst = (size_t)which * QSZ +
                             ((size_t)((bb * 12 + hh) * 197 + tok) * 64 + dd);
                qkv[dst] = f2bf(val);
            }
        }
    }
}

// ---------------- Kernel 3: attention, one block per head; K + V^T staged in LDS ----------
__global__ __launch_bounds__(256, 2) void attn_kernel(
        const unsigned short* __restrict__ qkv, float* __restrict__ out) {
    __shared__ __align__(16) unsigned short Ks[197 * 72];     // 28368 B
    __shared__ __align__(16) unsigned short Vt[64 * 216];     // 27648 B (stride 216: 2-way banks)
    __shared__ __align__(16) unsigned short Ps[4 * 16 * 136]; // 17408 B

    const int g = blockIdx.x;            // head index b*12+h
    const int b = g / 12, h = g - b * 12;
    const int t = threadIdx.x, w = t >> 6, lane = t & 63;
    const int quad = lane >> 4, l16 = lane & 15;

    const size_t headoff = (size_t)(g * 197) * 64;
    const unsigned short* Qg = qkv + headoff;
    const unsigned short* Kg = qkv + (size_t)QSZ + headoff;
    const unsigned short* Vg = qkv + (size_t)2 * QSZ + headoff;

    // stage K coalesced: 197 rows x 64 d, 16B chunks
    for (int idx = t; idx < 1576; idx += 256) {
        int row = idx >> 3, c8 = (idx & 7) * 8;
        *(uint4*)&Ks[row * 72 + c8] = *(const uint4*)(Kg + (size_t)row * 64 + c8);
    }
    // zero Vt pad cols 197..215 (PV reads them where p==0; avoid NaN*0)
    for (int idx = t; idx < 64 * 19; idx += 256) {
        int d = idx / 19, c = 197 + idx - d * 19;
        Vt[d * 216 + c] = 0;
    }
    // stage V transposed: coalesced 16B global read, scalar LDS scatter
    for (int idx = t; idx < 1576; idx += 256) {
        int tok = idx >> 3, d0 = (idx & 7) * 8;
        ushort4 v0 = *(const ushort4*)(Vg + (size_t)tok * 64 + d0);
        ushort4 v1 = *(const ushort4*)(Vg + (size_t)tok * 64 + d0 + 4);
        Vt[(d0 + 0) * 216 + tok] = v0.x;
        Vt[(d0 + 1) * 216 + tok] = v0.y;
        Vt[(d0 + 2) * 216 + tok] = v0.z;
        Vt[(d0 + 3) * 216 + tok] = v0.w;
        Vt[(d0 + 4) * 216 + tok] = v1.x;
        Vt[(d0 + 5) * 216 + tok] = v1.y;
        Vt[(d0 + 6) * 216 + tok] = v1.z;
        Vt[(d0 + 7) * 216 + tok] = v1.w;
    }
    __syncthreads();

    unsigned short* Pw = Ps + w * (16 * 136);

    // wave w handles q-tiles w, w+4, w+8, w+12 (13 tiles of 16 rows)
    for (int tile = w; tile < 13; tile += 4) {
        int rq = tile * 16 + l16;
        int tokq = rq < 197 ? rq : 196;
        bf16x8 aq0 = *(const bf16x8*)(Qg + (size_t)tokq * 64 + quad * 8);
        bf16x8 aq1 = *(const bf16x8*)(Qg + (size_t)tokq * 64 + 32 + quad * 8);

        // scores: 13 chunks of 16 kt-cols, K fragments from LDS
        f32x4 s[13];
#pragma unroll
        for (int c = 0; c < 13; ++c) {
            int krow = c * 16 + l16;
            if (krow > 196) krow = 196;             // clamped read; masked below
            bf16x8 kb0 = *(const bf16x8*)&Ks[krow * 72 + quad * 8];
            bf16x8 kb1 = *(const bf16x8*)&Ks[krow * 72 + 32 + quad * 8];
            f32x4 zz = (f32x4){0.f, 0.f, 0.f, 0.f};
            zz = __builtin_amdgcn_mfma_f32_16x16x32_bf16(aq0, kb0, zz, 0, 0, 0);
            zz = __builtin_amdgcn_mfma_f32_16x16x32_bf16(aq1, kb1, zz, 0, 0, 0);
            s[c] = zz;
        }
        if (l16 >= 5) { s[12][0] = -1e30f; s[12][1] = -1e30f; s[12][2] = -1e30f; s[12][3] = -1e30f; }

        // softmax over 208 cols (rows = quad*4+r, cols spread over l16)
        float mx[4], lsum[4];
#pragma unroll
        for (int r = 0; r < 4; ++r) {
            float m = s[0][r];
#pragma unroll
            for (int c = 1; c < 13; ++c) m = fmaxf(m, s[c][r]);
#pragma unroll
            for (int d = 1; d < 16; d <<= 1) m = fmaxf(m, __shfl_xor(m, d));
            mx[r] = m;
            lsum[r] = 0.f;
        }
#pragma unroll
        for (int c = 0; c < 13; ++c)
#pragma unroll
            for (int r = 0; r < 4; ++r) {
                float p = __expf(s[c][r] - mx[r]);
                s[c][r] = p;
                lsum[r] += p;
            }
#pragma unroll
        for (int r = 0; r < 4; ++r)
#pragma unroll
            for (int d = 1; d < 16; d <<= 1) lsum[r] += __shfl_xor(lsum[r], d);

        f32x4 o[4];
#pragma unroll
        for (int j = 0; j < 4; ++j) o[j] = (f32x4){0.f, 0.f, 0.f, 0.f};

        // PV pass 1: P cols 0..127 (same-wave LDS round trip, no barrier)
#pragma unroll
        for (int c = 0; c < 8; ++c)
#pragma unroll
            for (int r = 0; r < 4; ++r)
                Pw[(quad * 4 + r) * 136 + c * 16 + l16] = f2bf(s[c][r]);
#pragma unroll
        for (int kc = 0; kc < 4; ++kc) {
            int kof = kc * 32 + quad * 8;
            bf16x8 ap = *(const bf16x8*)&Pw[l16 * 136 + kof];
#pragma unroll
            for (int j = 0; j < 4; ++j) {
                bf16x8 bv = *(const bf16x8*)&Vt[(j * 16 + l16) * 216 + kof];
                o[j] = __builtin_amdgcn_mfma_f32_16x16x32_bf16(ap, bv, o[j], 0, 0, 0);
            }
        }
        // PV pass 2: P cols 128..207 -> buffer cols 0..79; cols 80..95 zeroed (p==0)
#pragma unroll
        for (int r = 0; r < 4; ++r)
            Pw[(quad * 4 + r) * 136 + 80 + l16] = 0;
#pragma unroll
        for (int c = 8; c < 13; ++c)
#pragma unroll
            for (int r = 0; r < 4; ++r)
                Pw[(quad * 4 + r) * 136 + (c - 8) * 16 + l16] = f2bf(s[c][r]);
#pragma unroll
        for (int kc = 0; kc < 3; ++kc) {
            int kofA = kc * 32 + quad * 8;
            // kc==2, quad>=2 -> kt 208..223 where p==0 exactly; clamp LDS read in-range
            int kofB = (kc == 2 && quad >= 2) ? 0 : kofA;
            bf16x8 ap = *(const bf16x8*)&Pw[l16 * 136 + kofA];
#pragma unroll
            for (int j = 0; j < 4; ++j) {
                bf16x8 bv = *(const bf16x8*)&Vt[(j * 16 + l16) * 216 + 128 + kofB];
                o[j] = __builtin_amdgcn_mfma_f32_16x16x32_bf16(ap, bv, o[j], 0, 0, 0);
            }
        }

        // epilogue: divide by l, store fp32 [B, tok, 768]
        int tokbase = tile * 16 + quad * 4;
#pragma unroll
        for (int r = 0; r < 4; ++r) {
            int tr = tokbase + r;
            if (tr >= 197) continue;
            float inv = 1.f / lsum[r];
#pragma unroll
            for (int j = 0; j < 4; ++j)
                out[((size_t)(b * 197 + tr)) * 768 + h * 64 + j * 16 + l16] = o[j][r] * inv;
        }
    }
}

extern "C" void kernel_launch(void* const* d_in, const int* in_sizes, int n_in,
                              void* d_out, int out_size, void* d_ws, size_t ws_size,
                              hipStream_t stream) {
    const float* X    = (const float*)d_in[0];   // [64,197,768]
    const float* W    = (const float*)d_in[1];   // [768,2304]
    const float* bias = (const float*)d_in[2];   // [2304]
    unsigned short* ws = (unsigned short*)d_ws;  // q | k | v planes
    float* out = (float*)d_out;                  // [64,197,768]

    // Xb and Wt live in d_out's dead space (overwritten by attn at the end).
    unsigned short* Xb = (unsigned short*)d_out;
    unsigned short* Wt = (unsigned short*)d_out + XB_ELEMS;

    x2bf_kernel<<<4800, 256, 0, stream>>>(X, Xb);
    wtrans_kernel<<<dim3(72, 24), dim3(32, 8), 0, stream>>>(W, Wt);
    qkv_gemm_kernel<<<450, 512, 0, stream>>>(Xb, Wt, bias, ws);
    attn_kernel<<<768, 256, 0, stream>>>(ws, out);
}

// Round 2
// 244.573 us; speedup vs baseline: 1.0741x; 1.0741x over previous
//
#include <hip/hip_runtime.h>

#define M_ROWS 12608          // 64*197
#define K_DIM  768
#define QSZ    9682944        // 64*12*197*64 elements per q/k/v plane
#define XB_ELEMS 9732096      // 12672*768 bf16 X copy (lives in d_out scratch)

typedef __bf16 bf16x8 __attribute__((ext_vector_type(8)));
typedef float  f32x4  __attribute__((ext_vector_type(4)));

__device__ __forceinline__ unsigned short f2bf(float f) {
    unsigned u = __builtin_bit_cast(unsigned, f);
    u += 0x7fffu + ((u >> 16) & 1u);          // RNE, inputs are finite
    return (unsigned short)(u >> 16);
}

__device__ __forceinline__ void gll16(const unsigned short* g, unsigned short* l) {
    __builtin_amdgcn_global_load_lds(
        (const __attribute__((address_space(1))) unsigned int*)g,
        (__attribute__((address_space(3))) unsigned int*)l, 16, 0, 0);
}

// ---------------- Kernel 0: X fp32 -> bf16 (stored in d_out scratch area) ----------------
__global__ void x2bf_kernel(const float* __restrict__ X, unsigned short* __restrict__ Xb) {
    size_t base = ((size_t)blockIdx.x * 256 + threadIdx.x) * 8;
    float4 a = *(const float4*)(X + base);
    float4 b = *(const float4*)(X + base + 4);
    ushort4 lo, hi;
    lo.x = f2bf(a.x); lo.y = f2bf(a.y); lo.z = f2bf(a.z); lo.w = f2bf(a.w);
    hi.x = f2bf(b.x); hi.y = f2bf(b.y); hi.z = f2bf(b.z); hi.w = f2bf(b.w);
    *(ushort4*)(Xb + base) = lo;
    *(ushort4*)(Xb + base + 4) = hi;
}

// ---------------- Kernel 1: W [768,2304] fp32 -> Wt [2304,768] bf16 ----------------
__global__ void wtrans_kernel(const float* __restrict__ W, unsigned short* __restrict__ Wt) {
    __shared__ float tile[32][33];
    int n0 = blockIdx.x * 32, k0 = blockIdx.y * 32;
    int tx = threadIdx.x, ty = threadIdx.y;
#pragma unroll
    for (int i = 0; i < 4; ++i)
        tile[ty + i * 8][tx] = W[(size_t)(k0 + ty + i * 8) * 2304 + n0 + tx];
    __syncthreads();
#pragma unroll
    for (int i = 0; i < 4; ++i)
        Wt[(size_t)(n0 + ty + i * 8) * K_DIM + k0 + tx] = f2bf(tile[tx][ty + i * 8]);
}

// ---------------- Kernel 2: QKV GEMM, 128x128 tile, 3-deep LDS ring, counted vmcnt ----
// Round-0 structure (proven 112us, 3 blocks/CU) + T3/T4 minimum pipeline:
//   iter kt: issue stage(kt+2) -> ds_read(kt) -> 16 MFMA -> vmcnt(4) -> s_barrier
// vmcnt(4) leaves the newest tile's 4 loads in flight (never drains to 0 in the loop).
// Ring distance 2: buf[(kt+2)%3] was last read at iter kt-1, barrier-separated. Safe.
// T1: bijective XCD-chunked swizzle (1782 = 8*222 + 6) so the 18 column-blocks of one
// A-panel share an XCD L2.
__global__ __launch_bounds__(256, 2) void qkv_gemm_kernel(
        const unsigned short* __restrict__ Xb, const unsigned short* __restrict__ Wt,
        const float* __restrict__ bias, unsigned short* __restrict__ qkv) {
    __shared__ __align__(16) unsigned short As[3][4096];   // 3 x 8 KB (k-major chunks)
    __shared__ __align__(16) unsigned short Bs[3][4096];   // 3 x 8 KB

    // XCD-chunked bijective swizzle: 1782 blocks, q=222, r=6
    const int lin = blockIdx.x;
    const int xcd = lin & 7, ix = lin >> 3;
    const int wg = (xcd < 6) ? xcd * 223 + ix : 1338 + (xcd - 6) * 222 + ix;
    const int by = wg / 18, bx = wg - by * 18;
    const int m0 = by * 128, n0 = bx * 128;

    const int t = threadIdx.x;
    const int w = t >> 6, lane = t & 63, quad = lane >> 4, l16 = lane & 15;
    const int wr = (w >> 1) * 64, wc = (w & 1) * 64;

    const int s0 = w * 128 + lane;
    const int r0 = s0 & 127, kc0 = s0 >> 7;
    const int s1 = s0 + 64;
    const int r1 = s1 & 127, kc1 = s1 >> 7;
    const unsigned short* a0 = Xb + (size_t)(m0 + r0) * K_DIM + kc0 * 8;
    const unsigned short* a1 = Xb + (size_t)(m0 + r1) * K_DIM + kc1 * 8;
    const unsigned short* b0 = Wt + (size_t)(n0 + r0) * K_DIM + kc0 * 8;
    const unsigned short* b1 = Wt + (size_t)(n0 + r1) * K_DIM + kc1 * 8;

    f32x4 acc[4][4];
#pragma unroll
    for (int i = 0; i < 4; ++i)
#pragma unroll
        for (int j = 0; j < 4; ++j) acc[i][j] = (f32x4){0.f, 0.f, 0.f, 0.f};

    // prologue: stage tiles 0 and 1; land tile 0, keep tile 1's 4 loads in flight
#pragma unroll
    for (int p = 0; p < 2; ++p) {
        gll16(a0 + p * 32, &As[p][w * 1024]);
        gll16(a1 + p * 32, &As[p][w * 1024 + 512]);
        gll16(b0 + p * 32, &Bs[p][w * 1024]);
        gll16(b1 + p * 32, &Bs[p][w * 1024 + 512]);
    }
    asm volatile("s_waitcnt vmcnt(4)" ::: "memory");
    __builtin_amdgcn_s_barrier();
    asm volatile("" ::: "memory");

#pragma unroll 3
    for (int kt = 0; kt < 24; ++kt) {
        const int cur = kt % 3;
        const int stb = (kt + 2) % 3;
        const int sk = (kt + 2 < 24 ? kt + 2 : 0) * 32;   // tail: dummy restage (dead)

        // issue next+1 tile staging first; overlaps ds_read + MFMA below
        gll16(a0 + sk, &As[stb][w * 1024]);
        gll16(a1 + sk, &As[stb][w * 1024 + 512]);
        gll16(b0 + sk, &Bs[stb][w * 1024]);
        gll16(b1 + sk, &Bs[stb][w * 1024 + 512]);

        bf16x8 af[4], bfr[4];
#pragma unroll
        for (int i = 0; i < 4; ++i)
            af[i] = *(const bf16x8*)&As[cur][quad * 1024 + (wr + i * 16 + l16) * 8];
#pragma unroll
        for (int j = 0; j < 4; ++j)
            bfr[j] = *(const bf16x8*)&Bs[cur][quad * 1024 + (wc + j * 16 + l16) * 8];

        __builtin_amdgcn_s_setprio(1);
#pragma unroll
        for (int i = 0; i < 4; ++i)
#pragma unroll
            for (int j = 0; j < 4; ++j)
                acc[i][j] = __builtin_amdgcn_mfma_f32_16x16x32_bf16(af[i], bfr[j], acc[i][j], 0, 0, 0);
        __builtin_amdgcn_s_setprio(0);

        // counted checkpoint: tile kt+1 landed; tile kt+2's 4 loads stay in flight
        asm volatile("s_waitcnt vmcnt(4)" ::: "memory");
        __builtin_amdgcn_s_barrier();
        asm volatile("" ::: "memory");
    }

    // epilogue: bias; fold 1/8 into q; q,k,v all stored [b,h][tok][d] (coalesced)
#pragma unroll
    for (int i = 0; i < 4; ++i) {
#pragma unroll
        for (int j = 0; j < 4; ++j) {
            int gn = n0 + wc + j * 16 + l16;
            int which = gn / 768;
            int rem = gn - which * 768;
            int hh = rem >> 6, dd = rem & 63;
            float bv = bias[gn];
#pragma unroll
            for (int r = 0; r < 4; ++r) {
                int gm = m0 + wr + i * 16 + quad * 4 + r;
                if (gm >= M_ROWS) continue;
                int bb = gm / 197;
                int tok = gm - bb * 197;
                float val = acc[i][j][r] + bv;
                if (which == 0) val *= 0.125f;
                size_t dst = (size_t)which * QSZ +
                             ((size_t)((bb * 12 + hh) * 197 + tok) * 64 + dd);
                qkv[dst] = f2bf(val);
            }
        }
    }
}

// ---------------- Kernel 3: attention, one block per head; K + V^T staged in LDS ----------
__global__ __launch_bounds__(256, 2) void attn_kernel(
        const unsigned short* __restrict__ qkv, float* __restrict__ out) {
    __shared__ __align__(16) unsigned short Ks[197 * 72];     // 28368 B
    __shared__ __align__(16) unsigned short Vt[64 * 216];     // 27648 B (stride 216: 2-way banks)
    __shared__ __align__(16) unsigned short Ps[4 * 16 * 136]; // 17408 B

    const int g = blockIdx.x;            // head index b*12+h
    const int b = g / 12, h = g - b * 12;
    const int t = threadIdx.x, w = t >> 6, lane = t & 63;
    const int quad = lane >> 4, l16 = lane & 15;

    const size_t headoff = (size_t)(g * 197) * 64;
    const unsigned short* Qg = qkv + headoff;
    const unsigned short* Kg = qkv + (size_t)QSZ + headoff;
    const unsigned short* Vg = qkv + (size_t)2 * QSZ + headoff;

    // stage K coalesced: 197 rows x 64 d, 16B chunks
    for (int idx = t; idx < 1576; idx += 256) {
        int row = idx >> 3, c8 = (idx & 7) * 8;
        *(uint4*)&Ks[row * 72 + c8] = *(const uint4*)(Kg + (size_t)row * 64 + c8);
    }
    // zero Vt pad cols 197..215 (PV reads them where p==0; avoid NaN*0)
    for (int idx = t; idx < 64 * 19; idx += 256) {
        int d = idx / 19, c = 197 + idx - d * 19;
        Vt[d * 216 + c] = 0;
    }
    // stage V transposed: coalesced 16B global read, scalar LDS scatter
    for (int idx = t; idx < 1576; idx += 256) {
        int tok = idx >> 3, d0 = (idx & 7) * 8;
        ushort4 v0 = *(const ushort4*)(Vg + (size_t)tok * 64 + d0);
        ushort4 v1 = *(const ushort4*)(Vg + (size_t)tok * 64 + d0 + 4);
        Vt[(d0 + 0) * 216 + tok] = v0.x;
        Vt[(d0 + 1) * 216 + tok] = v0.y;
        Vt[(d0 + 2) * 216 + tok] = v0.z;
        Vt[(d0 + 3) * 216 + tok] = v0.w;
        Vt[(d0 + 4) * 216 + tok] = v1.x;
        Vt[(d0 + 5) * 216 + tok] = v1.y;
        Vt[(d0 + 6) * 216 + tok] = v1.z;
        Vt[(d0 + 7) * 216 + tok] = v1.w;
    }
    __syncthreads();

    unsigned short* Pw = Ps + w * (16 * 136);

    // wave w handles q-tiles w, w+4, w+8, w+12 (13 tiles of 16 rows)
    for (int tile = w; tile < 13; tile += 4) {
        int rq = tile * 16 + l16;
        int tokq = rq < 197 ? rq : 196;
        bf16x8 aq0 = *(const bf16x8*)(Qg + (size_t)tokq * 64 + quad * 8);
        bf16x8 aq1 = *(const bf16x8*)(Qg + (size_t)tokq * 64 + 32 + quad * 8);

        // scores: 13 chunks of 16 kt-cols, K fragments from LDS
        f32x4 s[13];
#pragma unroll
        for (int c = 0; c < 13; ++c) {
            int krow = c * 16 + l16;
            if (krow > 196) krow = 196;             // clamped read; masked below
            bf16x8 kb0 = *(const bf16x8*)&Ks[krow * 72 + quad * 8];
            bf16x8 kb1 = *(const bf16x8*)&Ks[krow * 72 + 32 + quad * 8];
            f32x4 zz = (f32x4){0.f, 0.f, 0.f, 0.f};
            zz = __builtin_amdgcn_mfma_f32_16x16x32_bf16(aq0, kb0, zz, 0, 0, 0);
            zz = __builtin_amdgcn_mfma_f32_16x16x32_bf16(aq1, kb1, zz, 0, 0, 0);
            s[c] = zz;
        }
        if (l16 >= 5) { s[12][0] = -1e30f; s[12][1] = -1e30f; s[12][2] = -1e30f; s[12][3] = -1e30f; }

        // softmax over 208 cols (rows = quad*4+r, cols spread over l16)
        float mx[4], lsum[4];
#pragma unroll
        for (int r = 0; r < 4; ++r) {
            float m = s[0][r];
#pragma unroll
            for (int c = 1; c < 13; ++c) m = fmaxf(m, s[c][r]);
#pragma unroll
            for (int d = 1; d < 16; d <<= 1) m = fmaxf(m, __shfl_xor(m, d));
            mx[r] = m;
            lsum[r] = 0.f;
        }
#pragma unroll
        for (int c = 0; c < 13; ++c)
#pragma unroll
            for (int r = 0; r < 4; ++r) {
                float p = __expf(s[c][r] - mx[r]);
                s[c][r] = p;
                lsum[r] += p;
            }
#pragma unroll
        for (int r = 0; r < 4; ++r)
#pragma unroll
            for (int d = 1; d < 16; d <<= 1) lsum[r] += __shfl_xor(lsum[r], d);

        f32x4 o[4];
#pragma unroll
        for (int j = 0; j < 4; ++j) o[j] = (f32x4){0.f, 0.f, 0.f, 0.f};

        // PV pass 1: P cols 0..127 (same-wave LDS round trip, no barrier)
#pragma unroll
        for (int c = 0; c < 8; ++c)
#pragma unroll
            for (int r = 0; r < 4; ++r)
                Pw[(quad * 4 + r) * 136 + c * 16 + l16] = f2bf(s[c][r]);
#pragma unroll
        for (int kc = 0; kc < 4; ++kc) {
            int kof = kc * 32 + quad * 8;
            bf16x8 ap = *(const bf16x8*)&Pw[l16 * 136 + kof];
#pragma unroll
            for (int j = 0; j < 4; ++j) {
                bf16x8 bv = *(const bf16x8*)&Vt[(j * 16 + l16) * 216 + kof];
                o[j] = __builtin_amdgcn_mfma_f32_16x16x32_bf16(ap, bv, o[j], 0, 0, 0);
            }
        }
        // PV pass 2: P cols 128..207 -> buffer cols 0..79; cols 80..95 zeroed (p==0)
#pragma unroll
        for (int r = 0; r < 4; ++r)
            Pw[(quad * 4 + r) * 136 + 80 + l16] = 0;
#pragma unroll
        for (int c = 8; c < 13; ++c)
#pragma unroll
            for (int r = 0; r < 4; ++r)
                Pw[(quad * 4 + r) * 136 + (c - 8) * 16 + l16] = f2bf(s[c][r]);
#pragma unroll
        for (int kc = 0; kc < 3; ++kc) {
            int kofA = kc * 32 + quad * 8;
            // kc==2, quad>=2 -> kt 208..223 where p==0 exactly; clamp LDS read in-range
            int kofB = (kc == 2 && quad >= 2) ? 0 : kofA;
            bf16x8 ap = *(const bf16x8*)&Pw[l16 * 136 + kofA];
#pragma unroll
            for (int j = 0; j < 4; ++j) {
                bf16x8 bv = *(const bf16x8*)&Vt[(j * 16 + l16) * 216 + 128 + kofB];
                o[j] = __builtin_amdgcn_mfma_f32_16x16x32_bf16(ap, bv, o[j], 0, 0, 0);
            }
        }

        // epilogue: divide by l, store fp32 [B, tok, 768]
        int tokbase = tile * 16 + quad * 4;
#pragma unroll
        for (int r = 0; r < 4; ++r) {
            int tr = tokbase + r;
            if (tr >= 197) continue;
            float inv = 1.f / lsum[r];
#pragma unroll
            for (int j = 0; j < 4; ++j)
                out[((size_t)(b * 197 + tr)) * 768 + h * 64 + j * 16 + l16] = o[j][r] * inv;
        }
    }
}

extern "C" void kernel_launch(void* const* d_in, const int* in_sizes, int n_in,
                              void* d_out, int out_size, void* d_ws, size_t ws_size,
                              hipStream_t stream) {
    const float* X    = (const float*)d_in[0];   // [64,197,768]
    const float* W    = (const float*)d_in[1];   // [768,2304]
    const float* bias = (const float*)d_in[2];   // [2304]
    unsigned short* ws = (unsigned short*)d_ws;  // q | k | v planes
    float* out = (float*)d_out;                  // [64,197,768]

    // Xb and Wt live in d_out's dead space (overwritten by attn at the end).
    unsigned short* Xb = (unsigned short*)d_out;
    unsigned short* Wt = (unsigned short*)d_out + XB_ELEMS;

    x2bf_kernel<<<4728, 256, 0, stream>>>(X, Xb);
    wtrans_kernel<<<dim3(72, 24), dim3(32, 8), 0, stream>>>(W, Wt);
    qkv_gemm_kernel<<<1782, 256, 0, stream>>>(Xb, Wt, bias, ws);
    attn_kernel<<<768, 256, 0, stream>>>(ws, out);
}

// Round 3
// 227.993 us; speedup vs baseline: 1.1522x; 1.0727x over previous
//
#include <hip/hip_runtime.h>

#define M_ROWS 12608          // 64*197
#define K_DIM  768
#define QSZ    9682944        // 64*12*197*64 elements per q/k/v plane
#define XB_ELEMS 9732096      // 12672*768 bf16 X copy (lives in d_out scratch)

typedef __bf16 bf16x8 __attribute__((ext_vector_type(8)));
typedef float  f32x4  __attribute__((ext_vector_type(4)));

__device__ __forceinline__ unsigned short f2bf(float f) {
    unsigned u = __builtin_bit_cast(unsigned, f);
    u += 0x7fffu + ((u >> 16) & 1u);          // RNE, inputs are finite
    return (unsigned short)(u >> 16);
}

__device__ __forceinline__ void gll16(const unsigned short* g, unsigned short* l) {
    __builtin_amdgcn_global_load_lds(
        (const __attribute__((address_space(1))) unsigned int*)g,
        (__attribute__((address_space(3))) unsigned int*)l, 16, 0, 0);
}

// ---------------- Kernel 0: X fp32 -> bf16 (stored in d_out scratch area) ----------------
__global__ void x2bf_kernel(const float* __restrict__ X, unsigned short* __restrict__ Xb) {
    size_t base = ((size_t)blockIdx.x * 256 + threadIdx.x) * 8;
    float4 a = *(const float4*)(X + base);
    float4 b = *(const float4*)(X + base + 4);
    ushort4 lo, hi;
    lo.x = f2bf(a.x); lo.y = f2bf(a.y); lo.z = f2bf(a.z); lo.w = f2bf(a.w);
    hi.x = f2bf(b.x); hi.y = f2bf(b.y); hi.z = f2bf(b.z); hi.w = f2bf(b.w);
    *(ushort4*)(Xb + base) = lo;
    *(ushort4*)(Xb + base + 4) = hi;
}

// ---------------- Kernel 1: W [768,2304] fp32 -> Wt [2304,768] bf16 ----------------
__global__ void wtrans_kernel(const float* __restrict__ W, unsigned short* __restrict__ Wt) {
    __shared__ float tile[32][33];
    int n0 = blockIdx.x * 32, k0 = blockIdx.y * 32;
    int tx = threadIdx.x, ty = threadIdx.y;
#pragma unroll
    for (int i = 0; i < 4; ++i)
        tile[ty + i * 8][tx] = W[(size_t)(k0 + ty + i * 8) * 2304 + n0 + tx];
    __syncthreads();
#pragma unroll
    for (int i = 0; i < 4; ++i)
        Wt[(size_t)(n0 + ty + i * 8) * K_DIM + k0 + tx] = f2bf(tile[tx][ty + i * 8]);
}

// ---------------- Kernel 2: QKV GEMM, 128x128 tile, 2-buffer ring, overlap staging ----
// R0 structure + the one fix R0 needed: stage(kt+1) issued at TOP of iter kt, drained
// only at the BOTTOM (vmcnt(0) has just these 4 loads outstanding; the ds_read+MFMA
// body overlaps the staging latency). 32 KB LDS + 64 VGPR + 64 AGPR keeps 4 blocks/CU
// (launch_bounds(256,4) pins the register budget). Ring safety: buf[nxt] was last read
// one barrier ago. T1 bijective XCD-chunked swizzle kept (FETCH 101->61 MB, measured).
__global__ __launch_bounds__(256, 4) void qkv_gemm_kernel(
        const unsigned short* __restrict__ Xb, const unsigned short* __restrict__ Wt,
        const float* __restrict__ bias, unsigned short* __restrict__ qkv) {
    __shared__ __align__(16) unsigned short As[2][4096];   // 2 x 8 KB (k-major chunks)
    __shared__ __align__(16) unsigned short Bs[2][4096];   // 2 x 8 KB

    // XCD-chunked bijective swizzle: 1782 blocks, q=222, r=6
    const int lin = blockIdx.x;
    const int xcd = lin & 7, ix = lin >> 3;
    const int wg = (xcd < 6) ? xcd * 223 + ix : 1338 + (xcd - 6) * 222 + ix;
    const int by = wg / 18, bx = wg - by * 18;
    const int m0 = by * 128, n0 = bx * 128;

    const int t = threadIdx.x;
    const int w = t >> 6, lane = t & 63, quad = lane >> 4, l16 = lane & 15;
    const int wr = (w >> 1) * 64, wc = (w & 1) * 64;

    const int s0 = w * 128 + lane;
    const int r0 = s0 & 127, kc0 = s0 >> 7;
    const int s1 = s0 + 64;
    const int r1 = s1 & 127, kc1 = s1 >> 7;
    const unsigned short* a0 = Xb + (size_t)(m0 + r0) * K_DIM + kc0 * 8;
    const unsigned short* a1 = Xb + (size_t)(m0 + r1) * K_DIM + kc1 * 8;
    const unsigned short* b0 = Wt + (size_t)(n0 + r0) * K_DIM + kc0 * 8;
    const unsigned short* b1 = Wt + (size_t)(n0 + r1) * K_DIM + kc1 * 8;

    f32x4 acc[4][4];
#pragma unroll
    for (int i = 0; i < 4; ++i)
#pragma unroll
        for (int j = 0; j < 4; ++j) acc[i][j] = (f32x4){0.f, 0.f, 0.f, 0.f};

    // prologue: stage tile 0, land it (one-time full drain)
    gll16(a0, &As[0][w * 1024]);
    gll16(a1, &As[0][w * 1024 + 512]);
    gll16(b0, &Bs[0][w * 1024]);
    gll16(b1, &Bs[0][w * 1024 + 512]);
    asm volatile("s_waitcnt vmcnt(0)" ::: "memory");
    __builtin_amdgcn_s_barrier();
    asm volatile("" ::: "memory");

#pragma unroll 2
    for (int kt = 0; kt < 24; ++kt) {
        const int cur = kt & 1, nxt = cur ^ 1;
        const int sk = (kt + 1 < 24 ? kt + 1 : 0) * 32;   // tail: dummy restage (dead)

        // issue next tile's staging first; the whole body below overlaps its latency
        gll16(a0 + sk, &As[nxt][w * 1024]);
        gll16(a1 + sk, &As[nxt][w * 1024 + 512]);
        gll16(b0 + sk, &Bs[nxt][w * 1024]);
        gll16(b1 + sk, &Bs[nxt][w * 1024 + 512]);

        bf16x8 af[4], bfr[4];
#pragma unroll
        for (int i = 0; i < 4; ++i)
            af[i] = *(const bf16x8*)&As[cur][quad * 1024 + (wr + i * 16 + l16) * 8];
#pragma unroll
        for (int j = 0; j < 4; ++j)
            bfr[j] = *(const bf16x8*)&Bs[cur][quad * 1024 + (wc + j * 16 + l16) * 8];

#pragma unroll
        for (int i = 0; i < 4; ++i)
#pragma unroll
            for (int j = 0; j < 4; ++j)
                acc[i][j] = __builtin_amdgcn_mfma_f32_16x16x32_bf16(af[i], bfr[j], acc[i][j], 0, 0, 0);

        // drain this iter's 4 loads (latency already covered by the body) + publish
        asm volatile("s_waitcnt vmcnt(0)" ::: "memory");
        __builtin_amdgcn_s_barrier();
        asm volatile("" ::: "memory");
    }

    // epilogue: bias; fold 1/8 into q; q,k,v all stored [b,h][tok][d] (coalesced)
#pragma unroll
    for (int i = 0; i < 4; ++i) {
#pragma unroll
        for (int j = 0; j < 4; ++j) {
            int gn = n0 + wc + j * 16 + l16;
            int which = gn / 768;
            int rem = gn - which * 768;
            int hh = rem >> 6, dd = rem & 63;
            float bv = bias[gn];
#pragma unroll
            for (int r = 0; r < 4; ++r) {
                int gm = m0 + wr + i * 16 + quad * 4 + r;
                if (gm >= M_ROWS) continue;
                int bb = gm / 197;
                int tok = gm - bb * 197;
                float val = acc[i][j][r] + bv;
                if (which == 0) val *= 0.125f;
                size_t dst = (size_t)which * QSZ +
                             ((size_t)((bb * 12 + hh) * 197 + tok) * 64 + dd);
                qkv[dst] = f2bf(val);
            }
        }
    }
}

// ---------------- Kernel 3: attention, one block per head; K + V^T staged in LDS ----------
__global__ __launch_bounds__(256, 2) void attn_kernel(
        const unsigned short* __restrict__ qkv, float* __restrict__ out) {
    __shared__ __align__(16) unsigned short Ks[197 * 72];     // 28368 B
    __shared__ __align__(16) unsigned short Vt[64 * 216];     // 27648 B (stride 216: 2-way banks)
    __shared__ __align__(16) unsigned short Ps[4 * 16 * 136]; // 17408 B

    const int g = blockIdx.x;            // head index b*12+h
    const int b = g / 12, h = g - b * 12;
    const int t = threadIdx.x, w = t >> 6, lane = t & 63;
    const int quad = lane >> 4, l16 = lane & 15;

    const size_t headoff = (size_t)(g * 197) * 64;
    const unsigned short* Qg = qkv + headoff;
    const unsigned short* Kg = qkv + (size_t)QSZ + headoff;
    const unsigned short* Vg = qkv + (size_t)2 * QSZ + headoff;

    // stage K coalesced: 197 rows x 64 d, 16B chunks
    for (int idx = t; idx < 1576; idx += 256) {
        int row = idx >> 3, c8 = (idx & 7) * 8;
        *(uint4*)&Ks[row * 72 + c8] = *(const uint4*)(Kg + (size_t)row * 64 + c8);
    }
    // zero Vt pad cols 197..215 (PV reads them where p==0; avoid NaN*0)
    for (int idx = t; idx < 64 * 19; idx += 256) {
        int d = idx / 19, c = 197 + idx - d * 19;
        Vt[d * 216 + c] = 0;
    }
    // stage V transposed: coalesced 16B global read, scalar LDS scatter
    for (int idx = t; idx < 1576; idx += 256) {
        int tok = idx >> 3, d0 = (idx & 7) * 8;
        ushort4 v0 = *(const ushort4*)(Vg + (size_t)tok * 64 + d0);
        ushort4 v1 = *(const ushort4*)(Vg + (size_t)tok * 64 + d0 + 4);
        Vt[(d0 + 0) * 216 + tok] = v0.x;
        Vt[(d0 + 1) * 216 + tok] = v0.y;
        Vt[(d0 + 2) * 216 + tok] = v0.z;
        Vt[(d0 + 3) * 216 + tok] = v0.w;
        Vt[(d0 + 4) * 216 + tok] = v1.x;
        Vt[(d0 + 5) * 216 + tok] = v1.y;
        Vt[(d0 + 6) * 216 + tok] = v1.z;
        Vt[(d0 + 7) * 216 + tok] = v1.w;
    }
    __syncthreads();

    unsigned short* Pw = Ps + w * (16 * 136);

    // wave w handles q-tiles w, w+4, w+8, w+12 (13 tiles of 16 rows)
    for (int tile = w; tile < 13; tile += 4) {
        int rq = tile * 16 + l16;
        int tokq = rq < 197 ? rq : 196;
        bf16x8 aq0 = *(const bf16x8*)(Qg + (size_t)tokq * 64 + quad * 8);
        bf16x8 aq1 = *(const bf16x8*)(Qg + (size_t)tokq * 64 + 32 + quad * 8);

        // scores: 13 chunks of 16 kt-cols, K fragments from LDS
        f32x4 s[13];
#pragma unroll
        for (int c = 0; c < 13; ++c) {
            int krow = c * 16 + l16;
            if (krow > 196) krow = 196;             // clamped read; masked below
            bf16x8 kb0 = *(const bf16x8*)&Ks[krow * 72 + quad * 8];
            bf16x8 kb1 = *(const bf16x8*)&Ks[krow * 72 + 32 + quad * 8];
            f32x4 zz = (f32x4){0.f, 0.f, 0.f, 0.f};
            zz = __builtin_amdgcn_mfma_f32_16x16x32_bf16(aq0, kb0, zz, 0, 0, 0);
            zz = __builtin_amdgcn_mfma_f32_16x16x32_bf16(aq1, kb1, zz, 0, 0, 0);
            s[c] = zz;
        }
        if (l16 >= 5) { s[12][0] = -1e30f; s[12][1] = -1e30f; s[12][2] = -1e30f; s[12][3] = -1e30f; }

        // softmax over 208 cols (rows = quad*4+r, cols spread over l16)
        float mx[4], lsum[4];
#pragma unroll
        for (int r = 0; r < 4; ++r) {
            float m = s[0][r];
#pragma unroll
            for (int c = 1; c < 13; ++c) m = fmaxf(m, s[c][r]);
#pragma unroll
            for (int d = 1; d < 16; d <<= 1) m = fmaxf(m, __shfl_xor(m, d));
            mx[r] = m;
            lsum[r] = 0.f;
        }
#pragma unroll
        for (int c = 0; c < 13; ++c)
#pragma unroll
            for (int r = 0; r < 4; ++r) {
                float p = __expf(s[c][r] - mx[r]);
                s[c][r] = p;
                lsum[r] += p;
            }
#pragma unroll
        for (int r = 0; r < 4; ++r)
#pragma unroll
            for (int d = 1; d < 16; d <<= 1) lsum[r] += __shfl_xor(lsum[r], d);

        f32x4 o[4];
#pragma unroll
        for (int j = 0; j < 4; ++j) o[j] = (f32x4){0.f, 0.f, 0.f, 0.f};

        // PV pass 1: P cols 0..127 (same-wave LDS round trip, no barrier)
#pragma unroll
        for (int c = 0; c < 8; ++c)
#pragma unroll
            for (int r = 0; r < 4; ++r)
                Pw[(quad * 4 + r) * 136 + c * 16 + l16] = f2bf(s[c][r]);
#pragma unroll
        for (int kc = 0; kc < 4; ++kc) {
            int kof = kc * 32 + quad * 8;
            bf16x8 ap = *(const bf16x8*)&Pw[l16 * 136 + kof];
#pragma unroll
            for (int j = 0; j < 4; ++j) {
                bf16x8 bv = *(const bf16x8*)&Vt[(j * 16 + l16) * 216 + kof];
                o[j] = __builtin_amdgcn_mfma_f32_16x16x32_bf16(ap, bv, o[j], 0, 0, 0);
            }
        }
        // PV pass 2: P cols 128..207 -> buffer cols 0..79; cols 80..95 zeroed (p==0)
#pragma unroll
        for (int r = 0; r < 4; ++r)
            Pw[(quad * 4 + r) * 136 + 80 + l16] = 0;
#pragma unroll
        for (int c = 8; c < 13; ++c)
#pragma unroll
            for (int r = 0; r < 4; ++r)
                Pw[(quad * 4 + r) * 136 + (c - 8) * 16 + l16] = f2bf(s[c][r]);
#pragma unroll
        for (int kc = 0; kc < 3; ++kc) {
            int kofA = kc * 32 + quad * 8;
            // kc==2, quad>=2 -> kt 208..223 where p==0 exactly; clamp LDS read in-range
            int kofB = (kc == 2 && quad >= 2) ? 0 : kofA;
            bf16x8 ap = *(const bf16x8*)&Pw[l16 * 136 + kofA];
#pragma unroll
            for (int j = 0; j < 4; ++j) {
                bf16x8 bv = *(const bf16x8*)&Vt[(j * 16 + l16) * 216 + 128 + kofB];
                o[j] = __builtin_amdgcn_mfma_f32_16x16x32_bf16(ap, bv, o[j], 0, 0, 0);
            }
        }

        // epilogue: divide by l, store fp32 [B, tok, 768]
        int tokbase = tile * 16 + quad * 4;
#pragma unroll
        for (int r = 0; r < 4; ++r) {
            int tr = tokbase + r;
            if (tr >= 197) continue;
            float inv = 1.f / lsum[r];
#pragma unroll
            for (int j = 0; j < 4; ++j)
                out[((size_t)(b * 197 + tr)) * 768 + h * 64 + j * 16 + l16] = o[j][r] * inv;
        }
    }
}

extern "C" void kernel_launch(void* const* d_in, const int* in_sizes, int n_in,
                              void* d_out, int out_size, void* d_ws, size_t ws_size,
                              hipStream_t stream) {
    const float* X    = (const float*)d_in[0];   // [64,197,768]
    const float* W    = (const float*)d_in[1];   // [768,2304]
    const float* bias = (const float*)d_in[2];   // [2304]
    unsigned short* ws = (unsigned short*)d_ws;  // q | k | v planes
    float* out = (float*)d_out;                  // [64,197,768]

    // Xb and Wt live in d_out's dead space (overwritten by attn at the end).
    unsigned short* Xb = (unsigned short*)d_out;
    unsigned short* Wt = (unsigned short*)d_out + XB_ELEMS;

    x2bf_kernel<<<4728, 256, 0, stream>>>(X, Xb);
    wtrans_kernel<<<dim3(72, 24), dim3(32, 8), 0, stream>>>(W, Wt);
    qkv_gemm_kernel<<<1782, 256, 0, stream>>>(Xb, Wt, bias, ws);
    attn_kernel<<<768, 256, 0, stream>>>(ws, out);
}